// Round 11
// baseline (400.003 us; speedup 1.0000x reference)
//
#include <hip/hip_runtime.h>
#include <hip/hip_bf16.h>

// ---------------- problem constants ----------------
#define HD    1152
#define NHD   16        // heads
#define DH    72        // head dim
#define DHP   80        // padded head dim (5 x 16 for mfma K-chunks)
#define NB    16        // batch
#define SEQ   729
#define SP    736       // seq padded to x32 for K tiles
#define MTOT  (NB*SEQ)  // 11664
#define MPAD  11776     // 92 * 128
#define VROWS 96        // V d-rows padded to 3 x 32
// fold head_dim^-0.5 * log2(e) into Q so softmax runs in exp2 domain
#define QSCALE (0.117851130197757930f * 1.4426950408889634f)

typedef __attribute__((ext_vector_type(8))) short short8;
typedef __attribute__((ext_vector_type(4))) float f32x4;
typedef __attribute__((ext_vector_type(16))) float f32x16;
typedef __attribute__((ext_vector_type(4))) unsigned u32x4;
typedef unsigned short us;

__device__ __forceinline__ us f2bf(float x){
  unsigned u = __float_as_uint(x);
  u += 0x7FFFu + ((u >> 16) & 1u);   // RNE
  return (us)(u >> 16);
}

__device__ __forceinline__ unsigned cvtpk_bf16(float lo, float hi){
  unsigned r;
  asm("v_cvt_pk_bf16_f32 %0, %1, %2" : "=v"(r) : "v"(lo), "v"(hi));
  return r;
}

#define GLD16(g, s) __builtin_amdgcn_global_load_lds( \
    (const __attribute__((address_space(1))) void*)(g), \
    (__attribute__((address_space(3))) void*)(s), 16, 0, 0)

// ---------------- workspace layout (bytes) ----------------
#define OFF_HSB   ((size_t)0)                    // MPAD*HD*2        = 27131904
#define OFF_WQKV  ((size_t)27131904)             // 3456*HD*2        =  7962624
#define OFF_WO    ((size_t)35094528)             // HD*HD*2          =  2654208
#define OFF_Q     ((size_t)37748736)             // 256*SEQ*DHP*2    = 29859840
#define OFF_K     ((size_t)67608576)             // 256*SP*DHP*2     = 30146560
#define OFF_V     ((size_t)97755136)             // 256*VROWS*SP*2   = 36175872
#define WS_END    ((size_t)133931008)

// ---------------- merged prep: hs->bf16 convert + 4x weight transpose ----------------
// blocks [0, 13122): cvt of hs (4 floats/thread, exact fit)
// blocks [13122, 13122+4*1296): 32x32 transpose tiles of Wq/Wk/Wv/Wo
#define CVT_BLOCKS 13122
__global__ void prep_kernel(const float* __restrict__ hs, us* __restrict__ hsb,
                            const float* __restrict__ Wq, const float* __restrict__ Wk,
                            const float* __restrict__ Wv, const float* __restrict__ Wo,
                            us* __restrict__ wqkvT, us* __restrict__ woT){
  __shared__ float t[32][33];
  const int b = blockIdx.x, tid = threadIdx.x;
  if (b < CVT_BLOCKS){
    int i = b*256 + tid;     // exactly MTOT*HD/4 threads
    float4 v = ((const float4*)hs)[i];
    ushort4 o;
    o.x = f2bf(v.x); o.y = f2bf(v.y); o.z = f2bf(v.z); o.w = f2bf(v.w);
    ((ushort4*)hsb)[i] = o;
    return;
  }
  const int bb = b - CVT_BLOCKS;
  const int sel = bb / 1296, cell = bb % 1296;
  const int k0 = (cell/36)*32, n0 = (cell%36)*32;
  const float* W = (sel==0)?Wq:(sel==1)?Wk:(sel==2)?Wv:Wo;
  us* outT = (sel<3) ? (wqkvT + (size_t)sel*HD*HD) : woT;
  const int tx = tid & 31, ty = tid >> 5;   // (32, 8)
  #pragma unroll
  for (int j=0;j<32;j+=8) t[ty+j][tx] = W[(size_t)(k0+ty+j)*HD + n0 + tx];
  __syncthreads();
  #pragma unroll
  for (int j=0;j<32;j+=8) outT[(size_t)(n0+ty+j)*HD + k0 + tx] = f2bf(t[tx][ty+j]);
}

// ---------------- bf16 GEMM: C[M][N] = A[M][K] * BT[N][K]^T ----------------
// 128x128 tile, BK=64 (18 K-steps), counted 2-deep pipeline (vmcnt(8), never 0
// in loop), chunk^(row&7) XOR swizzle BOTH-sides (pre-swizzled global source for
// linear global_load_lds + same XOR on ds_read col) -> 0 bank conflicts (r8).
// 64 KB LDS -> 2 blocks/CU. MODE 0: O-proj -> fp32 out + bias.
// MODE 1: QKV -> scatter to padded Q/K/Vt + bias (+ zero Q d-pads, no memset).
template<int MODE>
__global__ __launch_bounds__(256, 2) void gemm64_kernel(
    const us* __restrict__ A, const us* __restrict__ BT,
    const float* __restrict__ bias_q, const float* __restrict__ bias_k,
    const float* __restrict__ bias_v,
    float* __restrict__ outF,
    us* __restrict__ Qp, us* __restrict__ Kp, us* __restrict__ Vt)
{
  constexpr int TILES_N = (MODE==1) ? 27 : 9;
  constexpr int NBLK = (MPAD/128)*TILES_N;
  constexpr int NT = HD/64;   // 18 K-steps

  // T1: bijective XCD-chunked swizzle (m204)
  int blk;
  {
    int orig = blockIdx.x;
    constexpr int q = NBLK >> 3, r = NBLK & 7;
    int xcd = orig & 7, idx = orig >> 3;
    blk = (xcd < r ? xcd*(q+1) : r*(q+1) + (xcd-r)*q) + idx;
  }
  const int tn = blk % TILES_N, tm = blk / TILES_N;
  const int tid = threadIdx.x, w = tid>>6, l = tid&63;
  const int lr = l&15, lg = l>>4;
  const int wm = w>>1, wn = w&1;

  __shared__ __align__(16) us As[2][128*64];   // [slot][row*64 + phys_chunk*8], 16 KB each
  __shared__ __align__(16) us Bs[2][128*64];

  f32x4 acc[4][4];
  #pragma unroll
  for (int i=0;i<4;i++)
    #pragma unroll
    for (int j=0;j<4;j++) acc[i][j] = (f32x4){0.f,0.f,0.f,0.f};

  // stage source: lane covers row w*32 + i*8 + (l>>3), phys chunk l&7;
  // content = logical chunk (l&7)^(row&7) -> pre-swizzled source (row&7 = (l>>3)&7)
  const int schunk = ((l&7) ^ ((l>>3)&7)) * 8;
  const us* gA = A  + (size_t)(tm*128 + w*32 + (l>>3))*HD + schunk;
  const us* gB = BT + (size_t)(tn*128 + w*32 + (l>>3))*HD + schunk;

#define STG64(kb, buf) do { \
    GLD16(gA + (kb),           &As[buf][(w*32 +  0)*64]); \
    GLD16(gA + (kb) +  8*HD,   &As[buf][(w*32 +  8)*64]); \
    GLD16(gA + (kb) + 16*HD,   &As[buf][(w*32 + 16)*64]); \
    GLD16(gA + (kb) + 24*HD,   &As[buf][(w*32 + 24)*64]); \
    GLD16(gB + (kb),           &Bs[buf][(w*32 +  0)*64]); \
    GLD16(gB + (kb) +  8*HD,   &Bs[buf][(w*32 +  8)*64]); \
    GLD16(gB + (kb) + 16*HD,   &Bs[buf][(w*32 + 16)*64]); \
    GLD16(gB + (kb) + 24*HD,   &Bs[buf][(w*32 + 24)*64]); \
  } while(0)

  // read-side swizzle: logical chunk cc = kk*4+lg, phys = cc ^ (row&7), row&7 = lr&7
  const int rsw = lr & 7;
  const int c0 = ((0 + lg) ^ rsw) * 8;
  const int c1 = ((4 + lg) ^ rsw) * 8;

#define RD_FRAGS(cur) \
    short8 af[4][2], bfr[4][2]; \
    _Pragma("unroll") \
    for (int mi=0;mi<4;mi++){ \
      const us* p = &As[cur][(wm*64 + mi*16 + lr)*64]; \
      af[mi][0] = *(const short8*)(p + c0); \
      af[mi][1] = *(const short8*)(p + c1); } \
    _Pragma("unroll") \
    for (int ni=0;ni<4;ni++){ \
      const us* p = &Bs[cur][(wn*64 + ni*16 + lr)*64]; \
      bfr[ni][0] = *(const short8*)(p + c0); \
      bfr[ni][1] = *(const short8*)(p + c1); }

#define MM64 do { \
    __builtin_amdgcn_s_setprio(1); \
    _Pragma("unroll") \
    for (int mi=0;mi<4;mi++) \
      _Pragma("unroll") \
      for (int ni=0;ni<4;ni++){ \
        acc[mi][ni] = __builtin_amdgcn_mfma_f32_16x16x32_bf16(af[mi][0], bfr[ni][0], acc[mi][ni], 0, 0, 0); \
        acc[mi][ni] = __builtin_amdgcn_mfma_f32_16x16x32_bf16(af[mi][1], bfr[ni][1], acc[mi][ni], 0, 0, 0); } \
    __builtin_amdgcn_s_setprio(0); \
  } while(0)

  // prologue: 2 K-steps in flight (16 gld_lds)
  STG64(0, 0);
  STG64(64, 1);

  for (int kt = 0; kt < NT-1; kt++){
    const int cur = kt & 1;
    asm volatile("s_waitcnt vmcnt(8)" ::: "memory");   // tile kt landed
    __builtin_amdgcn_sched_barrier(0);
    __builtin_amdgcn_s_barrier();
    __builtin_amdgcn_sched_barrier(0);

    RD_FRAGS(cur)

    asm volatile("s_waitcnt lgkmcnt(0)" ::: "memory"); // my reads done
    __builtin_amdgcn_sched_barrier(0);
    __builtin_amdgcn_s_barrier();                      // everyone's reads done
    __builtin_amdgcn_sched_barrier(0);

    if (kt + 2 < NT) STG64((kt+2)*64, cur);

    MM64;
  }
  { // tail kt = NT-1 (buf 1)
    constexpr int cur = (NT-1) & 1;
    asm volatile("s_waitcnt vmcnt(0)" ::: "memory");
    __builtin_amdgcn_sched_barrier(0);
    __builtin_amdgcn_s_barrier();
    __builtin_amdgcn_sched_barrier(0);
    RD_FRAGS(cur)
    MM64;
  }
#undef STG64
#undef RD_FRAGS
#undef MM64

  if (MODE == 0){
    #pragma unroll
    for (int mi=0;mi<4;mi++){
      #pragma unroll
      for (int j=0;j<4;j++){
        int m = tm*128 + wm*64 + mi*16 + lg*4 + j;
        if (m < MTOT){
          #pragma unroll
          for (int ni=0;ni<4;ni++){
            int n = tn*128 + wn*64 + ni*16 + lr;
            outF[(size_t)m*HD + n] = acc[mi][ni][j] + bias_q[n];
          }
        }
      }
    }
  } else {
    #pragma unroll
    for (int mi=0;mi<4;mi++){
      #pragma unroll
      for (int j=0;j<4;j++){
        int m = tm*128 + wm*64 + mi*16 + lg*4 + j;
        if (m >= MTOT) continue;
        int b = m / SEQ;
        int s = m - b*SEQ;
        #pragma unroll
        for (int ni=0;ni<4;ni++){
          int n = tn*128 + wn*64 + ni*16 + lr;
          int mat = n / HD;
          int c = n - mat*HD;
          int h = c / DH;
          int d = c - h*DH;
          const float* bias = (mat==0) ? bias_q : (mat==1) ? bias_k : bias_v;
          float v = acc[mi][ni][j] + bias[c];
          int bh = b*NHD + h;
          if (mat == 0){
            Qp[(size_t)bh*(SEQ*DHP) + (size_t)s*DHP + d] = f2bf(v*QSCALE);
            if (d < 8)  // zero the 8 d-pad cols (replaces the 30 MB memset)
              Qp[(size_t)bh*(SEQ*DHP) + (size_t)s*DHP + 72 + d] = 0;
          }
          else if (mat == 1) Kp[(size_t)bh*(SP*DHP)  + (size_t)s*DHP + d] = f2bf(v);
          else               Vt[(size_t)bh*(VROWS*SP) + (size_t)d*SP + s] = f2bf(v);
        }
      }
    }
  }
}

// ---------------- PV sub-tile: pack P (in-register) -> bf16 frags, 6 MFMAs ----------------
__device__ __forceinline__ void pv_subtile(const f32x16 s, const us* __restrict__ vcol,
                                           int hi, f32x16 (&o)[3]){
  unsigned A[4], B[4], xA[4], xB[4];
  #pragma unroll
  for (int g=0; g<4; g++){
    A[g]  = cvtpk_bf16(s[4*g+0], s[4*g+1]);
    B[g]  = cvtpk_bf16(s[4*g+2], s[4*g+3]);
    xA[g] = (unsigned)__shfl_xor((int)A[g], 32);
    xB[g] = (unsigned)__shfl_xor((int)B[g], 32);
  }
  __builtin_amdgcn_s_setprio(1);
  #pragma unroll
  for (int ks=0; ks<2; ks++){
    unsigned w0 = hi ? xA[2*ks+1] : A[2*ks];
    unsigned w1 = hi ? xB[2*ks+1] : B[2*ks];
    unsigned w2 = hi ? A[2*ks+1]  : xA[2*ks];
    unsigned w3 = hi ? B[2*ks+1]  : xB[2*ks];
    u32x4 pw = {w0, w1, w2, w3};
    short8 pa = __builtin_bit_cast(short8, pw);
    #pragma unroll
    for (int dt=0; dt<3; dt++){
      short8 vf = *(const short8*)(vcol + (size_t)(dt*32)*SP + ks*16 + hi*8);
      o[dt] = __builtin_amdgcn_mfma_f32_32x32x16_bf16(pa, vf, o[dt], 0, 0, 0);
    }
  }
  __builtin_amdgcn_s_setprio(0);
}

// ---------------- fused attention: 32 q-rows/wave, swapped QK^T, in-register softmax ----------------
__global__ __launch_bounds__(256) void attn_kernel(
    const us* __restrict__ Qp, const us* __restrict__ Kp,
    const us* __restrict__ Vt, us* __restrict__ ctx)
{
  const int blk = blockIdx.x;            // 0..1535
  const int xcd = blk & 7, ii = blk >> 3;
  const int bh  = xcd*32 + ii/6;
  const int qt6 = ii % 6;
  const int tid = threadIdx.x, w = tid>>6, l = tid&63;
  const int lane = l & 31, hi = l >> 5;

  const int qbase = (qt6*4 + w)*32;
  if (qbase >= SEQ) return;

  const us* Qb = Qp + (size_t)bh*(SEQ*DHP);
  const us* Kb = Kp + (size_t)bh*(SP*DHP);
  const us* Vb = Vt + (size_t)bh*(VROWS*SP);

  int qr = qbase + lane; if (qr > SEQ-1) qr = SEQ-1;
  short8 qf[5];
  #pragma unroll
  for (int c=0;c<5;c++) qf[c] = *(const short8*)(Qb + (size_t)qr*DHP + c*16 + hi*8);

  f32x16 o[3];
  #pragma unroll
  for (int dt=0; dt<3; dt++)
    #pragma unroll
    for (int r=0;r<16;r++) o[dt][r] = 0.f;

  float m = -1e30f, lsum = 0.f;

  for (int kt=0; kt<12; kt++){
    const int kb = kt*64;
    f32x16 s0, s1;
    #pragma unroll
    for (int r=0;r<16;r++){ s0[r]=0.f; s1[r]=0.f; }

    const us* krow0 = Kb + (size_t)(kb + lane)*DHP + hi*8;
    __builtin_amdgcn_s_setprio(1);
    #pragma unroll
    for (int c=0;c<5;c++){
      short8 kf = *(const short8*)(krow0 + c*16);
      s0 = __builtin_amdgcn_mfma_f32_32x32x16_bf16(kf, qf[c], s0, 0, 0, 0);
    }
    __builtin_amdgcn_s_setprio(0);
    if (kt < 11){
      const us* krow1 = krow0 + 32*DHP;
      __builtin_amdgcn_s_setprio(1);
      #pragma unroll
      for (int c=0;c<5;c++){
        short8 kf = *(const short8*)(krow1 + c*16);
        s1 = __builtin_amdgcn_mfma_f32_32x32x16_bf16(kf, qf[c], s1, 0, 0, 0);
      }
      __builtin_amdgcn_s_setprio(0);
    } else {
      #pragma unroll
      for (int r=0;r<16;r++){
        const int base = 704 + (r&3) + 8*(r>>2);
        s0[r] = (base + 4*hi >= SEQ) ? -1e30f : s0[r];
        s1[r] = -1e30f;
      }
    }

    float tmax = -1e30f;
    #pragma unroll
    for (int r=0;r<16;r++) tmax = fmaxf(tmax, fmaxf(s0[r], s1[r]));
    tmax = fmaxf(tmax, __shfl_xor(tmax, 32));

    if (!__all(tmax <= m + 8.0f)){       // T13 defer-max (exp2 domain, THR=8)
      float mn = fmaxf(m, tmax);
      float sc = exp2f(m - mn);
      m = mn;
      lsum *= sc;
      #pragma unroll
      for (int dt=0; dt<3; dt++)
        #pragma unroll
        for (int r=0;r<16;r++) o[dt][r] *= sc;
    }

    float su = 0.f;
    #pragma unroll
    for (int r=0;r<16;r++){ float pp = exp2f(s0[r]-m); s0[r]=pp; su += pp; }
    #pragma unroll
    for (int r=0;r<16;r++){ float pp = exp2f(s1[r]-m); s1[r]=pp; su += pp; }
    su += __shfl_xor(su, 32);
    lsum += su;

    const us* vcol = Vb + (size_t)lane*SP + kb;
    pv_subtile(s0, vcol, hi, o);
    if (kt < 11) pv_subtile(s1, vcol + 32, hi, o);
  }

  float linv = 1.0f / lsum;
  const int b = bh >> 4, h = bh & 15;
  #pragma unroll
  for (int r=0;r<16;r++){
    const int qloc = (r&3) + 8*(r>>2) + 4*hi;
    float lv = __shfl(linv, qloc);
    int q = qbase + qloc;
    if (q < SEQ){
      us* crow = ctx + ((size_t)(b*SEQ + q))*HD + h*DH;
      #pragma unroll
      for (int dt=0; dt<3; dt++){
        int d = dt*32 + lane;
        if (d < DH) crow[d] = f2bf(o[dt][r] * lv);
      }
    }
  }
}

// ---------------- launcher ----------------
extern "C" void kernel_launch(void* const* d_in, const int* in_sizes, int n_in,
                              void* d_out, int out_size, void* d_ws, size_t ws_size,
                              hipStream_t stream) {
  const float* hs = (const float*)d_in[0];
  const float* Wq = (const float*)d_in[1]; const float* bq = (const float*)d_in[2];
  const float* Wk = (const float*)d_in[3]; const float* bk = (const float*)d_in[4];
  const float* Wv = (const float*)d_in[5]; const float* bv = (const float*)d_in[6];
  const float* Wo = (const float*)d_in[7]; const float* bo = (const float*)d_in[8];
  float* out = (float*)d_out;
  char* ws = (char*)d_ws;
  if (ws_size < WS_END) return;

  us* hsb   = (us*)(ws + OFF_HSB);  // later reused as ctx
  us* wqkvT = (us*)(ws + OFF_WQKV);
  us* woT   = (us*)(ws + OFF_WO);
  us* Qp    = (us*)(ws + OFF_Q);
  us* Kp    = (us*)(ws + OFF_K);
  us* Vt    = (us*)(ws + OFF_V);
  us* ctx   = hsb;

  // 1. merged prep: hs -> bf16 + 4x weight transpose (one launch)
  prep_kernel<<<CVT_BLOCKS + 4*1296, 256, 0, stream>>>(hs, hsb, Wq, Wk, Wv, Wo,
                                                       wqkvT, woT);

  // 2. QKV projection GEMM (BK=64), scatter epilogue (also zeroes Q d-pads)
  gemm64_kernel<1><<<(MPAD/128)*27, 256, 0, stream>>>(hsb, wqkvT, bq, bk, bv,
                                                      nullptr, Qp, Kp, Vt);

  // 3. fused attention -> ctx [MTOT][1152] bf16 (reuses hsb buffer)
  attn_kernel<<<1536, 256, 0, stream>>>(Qp, Kp, Vt, ctx);

  // 4. output projection GEMM (BK=64) -> fp32 out + bo
  gemm64_kernel<0><<<(MPAD/128)*9, 256, 0, stream>>>(ctx, woT, bo, nullptr, nullptr,
                                                     out, nullptr, nullptr, nullptr);
}